// Round 1
// baseline (1851.740 us; speedup 1.0000x reference)
//
#include <hip/hip_runtime.h>

#define B_    2
#define S_    2048
#define D_    4096
#define NH_   32
#define NKV_  8
#define HD_   128
#define M_TOK 4096           // B_*S_
#define NQKV  6144           // (NH_+2*NKV_)*HD_
#define SCALE 0.08838834764831845f

typedef unsigned short u16;
typedef unsigned int   u32;
typedef __attribute__((ext_vector_type(8))) short short8;
typedef __attribute__((ext_vector_type(4))) float floatx4;

__device__ inline u16 f2bf(float f) {
    u32 u = __float_as_uint(f);
    u = (u + 0x7FFFu + ((u >> 16) & 1u)) >> 16;
    return (u16)u;
}
__device__ inline float bf2f(u16 u) {
    return __uint_as_float(((u32)u) << 16);
}

// ---------------------------------------------------------------------------
// B^T GEMM: C[m,n] = sum_k A[m,k] * W[n,k].  W rows come from up to 3 weight
// tensors split at row nb0/nb1 (for fused wq|wk|wv).  128x128 tile, BK=32,
// 4 waves each computing a 64x64 quadrant as 4x4 mfma_f32_16x16x32_bf16.
// ---------------------------------------------------------------------------
template<bool A_BF16, bool OUT_F32>
__global__ __launch_bounds__(256) void gemm_bt(
    const void* __restrict__ Ap,
    const float* __restrict__ B0, const float* __restrict__ B1,
    const float* __restrict__ B2, int nb0, int nb1,
    void* __restrict__ Cp, int M, int N, int K)
{
    __shared__ __align__(16) u16 As[128][40];   // +8 pad: frag reads 2-way max
    __shared__ __align__(16) u16 Bs[128][40];

    const int tid  = threadIdx.x;
    const int lane = tid & 63, wave = tid >> 6;
    const int quad = lane >> 4, l16 = lane & 15;
    const int m0 = blockIdx.y * 128, n0 = blockIdx.x * 128;
    const int wm = (wave >> 1) * 64, wn = (wave & 1) * 64;

    floatx4 acc[4][4];
    #pragma unroll
    for (int i = 0; i < 4; ++i)
        #pragma unroll
        for (int j = 0; j < 4; ++j) acc[i][j] = (floatx4){0.f, 0.f, 0.f, 0.f};

    for (int k0 = 0; k0 < K; k0 += 32) {
        // ---- stage A tile (128 rows x 32 k)
        if constexpr (!A_BF16) {
            const float* A = (const float*)Ap;
            int row = tid >> 3, cg = tid & 7;
            #pragma unroll
            for (int it = 0; it < 4; ++it, row += 32) {
                float4 v = *(const float4*)(A + (size_t)(m0 + row) * K + k0 + cg * 4);
                u32 p01 = (u32)f2bf(v.x) | ((u32)f2bf(v.y) << 16);
                u32 p23 = (u32)f2bf(v.z) | ((u32)f2bf(v.w) << 16);
                *(uint2*)&As[row][cg * 4] = make_uint2(p01, p23);
            }
        } else {
            const u16* A = (const u16*)Ap;
            int row = tid >> 2, cg = tid & 3;
            #pragma unroll
            for (int it = 0; it < 2; ++it, row += 64) {
                *(short8*)&As[row][cg * 8] =
                    *(const short8*)(A + (size_t)(m0 + row) * K + k0 + cg * 8);
            }
        }
        // ---- stage B tile (weights, always fp32)
        {
            int row = tid >> 3, cg = tid & 7;
            #pragma unroll
            for (int it = 0; it < 4; ++it, row += 32) {
                int rr = n0 + row;
                const float* src;
                if (rr < nb0)      src = B0 + (size_t)rr * K;
                else if (rr < nb1) src = B1 + (size_t)(rr - nb0) * K;
                else               src = B2 + (size_t)(rr - nb1) * K;
                float4 v = *(const float4*)(src + k0 + cg * 4);
                u32 p01 = (u32)f2bf(v.x) | ((u32)f2bf(v.y) << 16);
                u32 p23 = (u32)f2bf(v.z) | ((u32)f2bf(v.w) << 16);
                *(uint2*)&Bs[row][cg * 4] = make_uint2(p01, p23);
            }
        }
        __syncthreads();

        short8 af[4], bfv[4];
        #pragma unroll
        for (int i = 0; i < 4; ++i)
            af[i] = *(const short8*)&As[wm + i * 16 + l16][quad * 8];
        #pragma unroll
        for (int j = 0; j < 4; ++j)
            bfv[j] = *(const short8*)&Bs[wn + j * 16 + l16][quad * 8];
        #pragma unroll
        for (int i = 0; i < 4; ++i)
            #pragma unroll
            for (int j = 0; j < 4; ++j)
                acc[i][j] = __builtin_amdgcn_mfma_f32_16x16x32_bf16(
                    af[i], bfv[j], acc[i][j], 0, 0, 0);
        __syncthreads();
    }

    // epilogue: C/D layout col=lane&15, row=quad*4+reg
    #pragma unroll
    for (int i = 0; i < 4; ++i)
        #pragma unroll
        for (int j = 0; j < 4; ++j)
            #pragma unroll
            for (int r = 0; r < 4; ++r) {
                int row = m0 + wm + i * 16 + quad * 4 + r;
                int col = n0 + wn + j * 16 + l16;
                float v = acc[i][j][r];
                if constexpr (OUT_F32)
                    ((float*)Cp)[(size_t)row * N + col] = v;
                else
                    ((u16*)Cp)[(size_t)row * N + col] = f2bf(v);
            }
}

// ---------------------------------------------------------------------------
// RoPE + head-major reshape for Q and K.  cos[j+64]==cos[j], sin likewise.
// ---------------------------------------------------------------------------
__global__ __launch_bounds__(256) void rope_reshape(
    const u16* __restrict__ qkv, const float* __restrict__ cosp,
    const float* __restrict__ sinp, u16* __restrict__ Q, u16* __restrict__ Kb)
{
    const size_t QN = (size_t)M_TOK * NH_ * 64;   // 8388608
    size_t id = (size_t)blockIdx.x * 256 + threadIdx.x;
    if (id < QN) {
        int j = id & 63; int h = (id >> 6) & (NH_ - 1); int tok = (int)(id >> 11);
        int b = tok >> 11, s = tok & (S_ - 1);
        float c  = cosp[(size_t)tok * HD_ + j];
        float sn = sinp[(size_t)tok * HD_ + j];
        float x1 = bf2f(qkv[(size_t)tok * NQKV + h * HD_ + j]);
        float x2 = bf2f(qkv[(size_t)tok * NQKV + h * HD_ + 64 + j]);
        size_t o = ((size_t)(b * NH_ + h) * S_ + s) * HD_ + j;
        Q[o]      = f2bf(x1 * c - x2 * sn);
        Q[o + 64] = f2bf(x2 * c + x1 * sn);
    } else {
        size_t kid = id - QN;
        int j = kid & 63; int h = (kid >> 6) & (NKV_ - 1); int tok = (int)(kid >> 9);
        int b = tok >> 11, s = tok & (S_ - 1);
        float c  = cosp[(size_t)tok * HD_ + j];
        float sn = sinp[(size_t)tok * HD_ + j];
        float x1 = bf2f(qkv[(size_t)tok * NQKV + 4096 + h * HD_ + j]);
        float x2 = bf2f(qkv[(size_t)tok * NQKV + 4096 + h * HD_ + 64 + j]);
        size_t o = ((size_t)(b * NKV_ + h) * S_ + s) * HD_ + j;
        Kb[o]      = f2bf(x1 * c - x2 * sn);
        Kb[o + 64] = f2bf(x2 * c + x1 * sn);
    }
}

// ---------------------------------------------------------------------------
// V transpose: qkv[...,5120+h*128+d] -> Vt[b,hk,d,s]  (LDS-tiled 128x128)
// ---------------------------------------------------------------------------
__global__ __launch_bounds__(256) void v_transpose(
    const u16* __restrict__ qkv, u16* __restrict__ Vt)
{
    __shared__ __align__(16) u16 T[128][136];
    int bidx = blockIdx.x;
    int st = bidx & 15; int h = (bidx >> 4) & 7; int b = bidx >> 7;
    int s0 = st * 128;
    int tid = threadIdx.x;
    #pragma unroll
    for (int i = 0; i < 8; ++i) {
        int row = i * 16 + (tid >> 4); int cg = tid & 15;
        const u16* src = qkv + (size_t)(b * S_ + s0 + row) * NQKV + 5120 + h * HD_ + cg * 8;
        *(short8*)&T[row][cg * 8] = *(const short8*)src;
    }
    __syncthreads();
    #pragma unroll
    for (int i = 0; i < 8; ++i) {
        int d = i * 16 + (tid >> 4); int cg = tid & 15;
        __align__(16) u16 tmp[8];
        #pragma unroll
        for (int j = 0; j < 8; ++j) tmp[j] = T[cg * 8 + j][d];
        *(short8*)(Vt + ((size_t)(b * NKV_ + h) * HD_ + d) * S_ + s0 + cg * 8) =
            *(short8*)tmp;
    }
}

// ---------------------------------------------------------------------------
// Per-wave causal flash attention.  Wave handles 16 q-rows; kv-blocks of 32.
// Q/K/Vt fragments load directly from global (layouts match MFMA lane maps).
// P does C->A layout round-trip through per-wave LDS.
// ---------------------------------------------------------------------------
__global__ __launch_bounds__(256) void flash_attn(
    const u16* __restrict__ Q, const u16* __restrict__ Kb,
    const u16* __restrict__ Vt, u16* __restrict__ AO)
{
    __shared__ __align__(16) u16 Pl[4][16 * 32];
    const int tid  = threadIdx.x;
    const int wave = tid >> 6, lane = tid & 63;
    const int quad = lane >> 4, l16 = lane & 15;
    int gw = blockIdx.x * 4 + wave;
    int qt = gw & (S_ / 16 - 1);
    int h  = (gw >> 7) & (NH_ - 1);
    int b  = gw >> 12;
    int q0 = qt * 16;
    int hk = h >> 2;

    const u16* Qp = Q + ((size_t)(b * NH_ + h) * S_ + q0 + l16) * HD_ + quad * 8;
    short8 qf[4];
    #pragma unroll
    for (int c = 0; c < 4; ++c) qf[c] = *(const short8*)(Qp + c * 32);

    const u16* Kbase = Kb + (size_t)(b * NKV_ + hk) * S_ * HD_;
    const u16* Vbase = Vt + (size_t)(b * NKV_ + hk) * HD_ * S_;

    float mrow[4] = {-1e30f, -1e30f, -1e30f, -1e30f};
    float lrow[4] = {0.f, 0.f, 0.f, 0.f};
    floatx4 o[8];
    #pragma unroll
    for (int nc = 0; nc < 8; ++nc) o[nc] = (floatx4){0.f, 0.f, 0.f, 0.f};

    u16* Pw = &Pl[wave][0];
    int tmaxb = (q0 + 15) >> 5;
    for (int t = 0; t <= tmaxb; ++t) {
        int kb = t * 32;
        floatx4 s0 = (floatx4){0.f, 0.f, 0.f, 0.f};
        floatx4 s1 = (floatx4){0.f, 0.f, 0.f, 0.f};
        const u16* Kp0 = Kbase + (size_t)(kb + l16) * HD_ + quad * 8;
        const u16* Kp1 = Kp0 + 16 * HD_;
        #pragma unroll
        for (int c = 0; c < 4; ++c)
            s0 = __builtin_amdgcn_mfma_f32_16x16x32_bf16(
                qf[c], *(const short8*)(Kp0 + c * 32), s0, 0, 0, 0);
        #pragma unroll
        for (int c = 0; c < 4; ++c)
            s1 = __builtin_amdgcn_mfma_f32_16x16x32_bf16(
                qf[c], *(const short8*)(Kp1 + c * 32), s1, 0, 0, 0);

        int kv0 = kb + l16, kv1 = kb + 16 + l16;
        float bm[4], al[4], p0v[4], p1v[4], rs[4];
        #pragma unroll
        for (int r = 0; r < 4; ++r) {
            int qpos = q0 + quad * 4 + r;
            p0v[r] = (kv0 <= qpos) ? s0[r] * SCALE : -1e30f;
            p1v[r] = (kv1 <= qpos) ? s1[r] * SCALE : -1e30f;
            bm[r] = fmaxf(p0v[r], p1v[r]);
        }
        #pragma unroll
        for (int off = 8; off; off >>= 1)
            #pragma unroll
            for (int r = 0; r < 4; ++r)
                bm[r] = fmaxf(bm[r], __shfl_xor(bm[r], off, 16));
        #pragma unroll
        for (int r = 0; r < 4; ++r) {
            float mn = fmaxf(mrow[r], bm[r]);
            al[r] = __expf(mrow[r] - mn);
            mrow[r] = mn;
            float e0 = __expf(p0v[r] - mn), e1 = __expf(p1v[r] - mn);
            p0v[r] = e0; p1v[r] = e1;
            rs[r] = e0 + e1;
        }
        #pragma unroll
        for (int off = 8; off; off >>= 1)
            #pragma unroll
            for (int r = 0; r < 4; ++r) rs[r] += __shfl_xor(rs[r], off, 16);
        #pragma unroll
        for (int r = 0; r < 4; ++r) lrow[r] = lrow[r] * al[r] + rs[r];
        #pragma unroll
        for (int nc = 0; nc < 8; ++nc)
            #pragma unroll
            for (int r = 0; r < 4; ++r) o[nc][r] *= al[r];

        // P: C-layout -> LDS -> A-layout fragment
        #pragma unroll
        for (int r = 0; r < 4; ++r) {
            int row = quad * 4 + r;
            Pw[row * 32 + l16]      = f2bf(p0v[r]);
            Pw[row * 32 + 16 + l16] = f2bf(p1v[r]);
        }
        short8 pf = *(const short8*)(Pw + l16 * 32 + quad * 8);
        #pragma unroll
        for (int nc = 0; nc < 8; ++nc) {
            short8 vf = *(const short8*)(
                Vbase + (size_t)(nc * 16 + l16) * S_ + kb + quad * 8);
            o[nc] = __builtin_amdgcn_mfma_f32_16x16x32_bf16(pf, vf, o[nc], 0, 0, 0);
        }
    }

    #pragma unroll
    for (int r = 0; r < 4; ++r) lrow[r] = 1.0f / lrow[r];
    #pragma unroll
    for (int nc = 0; nc < 8; ++nc)
        #pragma unroll
        for (int r = 0; r < 4; ++r) {
            int row = quad * 4 + r;
            int col = h * HD_ + nc * 16 + l16;
            AO[((size_t)(b * S_) + q0 + row) * (NH_ * HD_) + col] =
                f2bf(o[nc][r] * lrow[r]);
        }
}

// ---------------------------------------------------------------------------
extern "C" void kernel_launch(void* const* d_in, const int* in_sizes, int n_in,
                              void* d_out, int out_size, void* d_ws, size_t ws_size,
                              hipStream_t stream)
{
    const float* hs   = (const float*)d_in[0];
    const float* cosp = (const float*)d_in[1];
    const float* sinp = (const float*)d_in[2];
    const float* wq   = (const float*)d_in[3];
    const float* wk   = (const float*)d_in[4];
    const float* wv   = (const float*)d_in[5];
    const float* wo   = (const float*)d_in[6];
    float* out = (float*)d_out;
    char* ws = (char*)d_ws;

    // workspace layout (96 MB total):
    u16* qkv_raw = (u16*)ws;                                  // 48 MB [4096][6144]
    u16* AO      = (u16*)ws;                                  // 32 MB, reuses qkv_raw
    u16* Qb = (u16*)(ws + (size_t)48 * 1024 * 1024);          // 32 MB [B,NH,S,HD]
    u16* Kb = (u16*)(ws + (size_t)80 * 1024 * 1024);          //  8 MB [B,NKV,S,HD]
    u16* Vt = (u16*)(ws + (size_t)88 * 1024 * 1024);          //  8 MB [B,NKV,HD,S]

    // 1) fused QKV projection: [4096,4096] x [6144,4096]^T -> bf16 raw
    gemm_bt<false, false><<<dim3(NQKV / 128, M_TOK / 128), 256, 0, stream>>>(
        hs, wq, wk, wv, NH_ * HD_, NH_ * HD_ + NKV_ * HD_,
        qkv_raw, M_TOK, NQKV, D_);

    // 2) RoPE + reshape for Q,K   (8388608 + 2097152 threads)
    rope_reshape<<<40960, 256, 0, stream>>>(qkv_raw, cosp, sinp, Qb, Kb);

    // 3) V transpose -> [B,NKV,HD,S]
    v_transpose<<<256, 256, 0, stream>>>(qkv_raw, Vt);

    // 4) causal GQA flash attention -> AO [4096, 4096] bf16
    flash_attn<<<2048, 256, 0, stream>>>(Qb, Kb, Vt, AO);

    // 5) output projection: AO x wo^T -> d_out fp32
    gemm_bt<true, true><<<dim3(D_ / 128, M_TOK / 128), 256, 0, stream>>>(
        AO, wo, wo, wo, D_, 2 * D_, out, M_TOK, D_, NH_ * HD_);
}

// Round 2
// 1434.741 us; speedup vs baseline: 1.2906x; 1.2906x over previous
//
#include <hip/hip_runtime.h>

#define B_    2
#define S_    2048
#define D_    4096
#define NH_   32
#define NKV_  8
#define HD_   128
#define M_TOK 4096           // B_*S_
#define NQKV  6144           // (NH_+2*NKV_)*HD_
#define SCALE 0.08838834764831845f

typedef unsigned short u16;
typedef unsigned int   u32;
typedef __attribute__((ext_vector_type(8))) short short8;
typedef __attribute__((ext_vector_type(4))) float floatx4;

__device__ inline u16 f2bf(float f) {
    u32 u = __float_as_uint(f);
    u = (u + 0x7FFFu + ((u >> 16) & 1u)) >> 16;
    return (u16)u;
}
__device__ inline float bf2f(u16 u) {
    return __uint_as_float(((u32)u) << 16);
}

// ---------------------------------------------------------------------------
// B^T GEMM (unchanged from round 1): C[m,n] = sum_k A[m,k] * W[n,k].
// ---------------------------------------------------------------------------
template<bool A_BF16, bool OUT_F32>
__global__ __launch_bounds__(256) void gemm_bt(
    const void* __restrict__ Ap,
    const float* __restrict__ B0, const float* __restrict__ B1,
    const float* __restrict__ B2, int nb0, int nb1,
    void* __restrict__ Cp, int M, int N, int K)
{
    __shared__ __align__(16) u16 As[128][40];
    __shared__ __align__(16) u16 Bs[128][40];

    const int tid  = threadIdx.x;
    const int lane = tid & 63, wave = tid >> 6;
    const int quad = lane >> 4, l16 = lane & 15;
    const int m0 = blockIdx.y * 128, n0 = blockIdx.x * 128;
    const int wm = (wave >> 1) * 64, wn = (wave & 1) * 64;

    floatx4 acc[4][4];
    #pragma unroll
    for (int i = 0; i < 4; ++i)
        #pragma unroll
        for (int j = 0; j < 4; ++j) acc[i][j] = (floatx4){0.f, 0.f, 0.f, 0.f};

    for (int k0 = 0; k0 < K; k0 += 32) {
        if constexpr (!A_BF16) {
            const float* A = (const float*)Ap;
            int row = tid >> 3, cg = tid & 7;
            #pragma unroll
            for (int it = 0; it < 4; ++it, row += 32) {
                float4 v = *(const float4*)(A + (size_t)(m0 + row) * K + k0 + cg * 4);
                u32 p01 = (u32)f2bf(v.x) | ((u32)f2bf(v.y) << 16);
                u32 p23 = (u32)f2bf(v.z) | ((u32)f2bf(v.w) << 16);
                *(uint2*)&As[row][cg * 4] = make_uint2(p01, p23);
            }
        } else {
            const u16* A = (const u16*)Ap;
            int row = tid >> 2, cg = tid & 3;
            #pragma unroll
            for (int it = 0; it < 2; ++it, row += 64) {
                *(short8*)&As[row][cg * 8] =
                    *(const short8*)(A + (size_t)(m0 + row) * K + k0 + cg * 8);
            }
        }
        {
            int row = tid >> 3, cg = tid & 7;
            #pragma unroll
            for (int it = 0; it < 4; ++it, row += 32) {
                int rr = n0 + row;
                const float* src;
                if (rr < nb0)      src = B0 + (size_t)rr * K;
                else if (rr < nb1) src = B1 + (size_t)(rr - nb0) * K;
                else               src = B2 + (size_t)(rr - nb1) * K;
                float4 v = *(const float4*)(src + k0 + cg * 4);
                u32 p01 = (u32)f2bf(v.x) | ((u32)f2bf(v.y) << 16);
                u32 p23 = (u32)f2bf(v.z) | ((u32)f2bf(v.w) << 16);
                *(uint2*)&Bs[row][cg * 4] = make_uint2(p01, p23);
            }
        }
        __syncthreads();

        short8 af[4], bfv[4];
        #pragma unroll
        for (int i = 0; i < 4; ++i)
            af[i] = *(const short8*)&As[wm + i * 16 + l16][quad * 8];
        #pragma unroll
        for (int j = 0; j < 4; ++j)
            bfv[j] = *(const short8*)&Bs[wn + j * 16 + l16][quad * 8];
        #pragma unroll
        for (int i = 0; i < 4; ++i)
            #pragma unroll
            for (int j = 0; j < 4; ++j)
                acc[i][j] = __builtin_amdgcn_mfma_f32_16x16x32_bf16(
                    af[i], bfv[j], acc[i][j], 0, 0, 0);
        __syncthreads();
    }

    #pragma unroll
    for (int i = 0; i < 4; ++i)
        #pragma unroll
        for (int j = 0; j < 4; ++j)
            #pragma unroll
            for (int r = 0; r < 4; ++r) {
                int row = m0 + wm + i * 16 + quad * 4 + r;
                int col = n0 + wn + j * 16 + l16;
                float v = acc[i][j][r];
                if constexpr (OUT_F32)
                    ((float*)Cp)[(size_t)row * N + col] = v;
                else
                    ((u16*)Cp)[(size_t)row * N + col] = f2bf(v);
            }
}

// ---------------------------------------------------------------------------
// RoPE + head-major reshape for Q and K (unchanged).
// ---------------------------------------------------------------------------
__global__ __launch_bounds__(256) void rope_reshape(
    const u16* __restrict__ qkv, const float* __restrict__ cosp,
    const float* __restrict__ sinp, u16* __restrict__ Q, u16* __restrict__ Kb)
{
    const size_t QN = (size_t)M_TOK * NH_ * 64;
    size_t id = (size_t)blockIdx.x * 256 + threadIdx.x;
    if (id < QN) {
        int j = id & 63; int h = (id >> 6) & (NH_ - 1); int tok = (int)(id >> 11);
        int b = tok >> 11, s = tok & (S_ - 1);
        float c  = cosp[(size_t)tok * HD_ + j];
        float sn = sinp[(size_t)tok * HD_ + j];
        float x1 = bf2f(qkv[(size_t)tok * NQKV + h * HD_ + j]);
        float x2 = bf2f(qkv[(size_t)tok * NQKV + h * HD_ + 64 + j]);
        size_t o = ((size_t)(b * NH_ + h) * S_ + s) * HD_ + j;
        Q[o]      = f2bf(x1 * c - x2 * sn);
        Q[o + 64] = f2bf(x2 * c + x1 * sn);
    } else {
        size_t kid = id - QN;
        int j = kid & 63; int h = (kid >> 6) & (NKV_ - 1); int tok = (int)(kid >> 9);
        int b = tok >> 11, s = tok & (S_ - 1);
        float c  = cosp[(size_t)tok * HD_ + j];
        float sn = sinp[(size_t)tok * HD_ + j];
        float x1 = bf2f(qkv[(size_t)tok * NQKV + 4096 + h * HD_ + j]);
        float x2 = bf2f(qkv[(size_t)tok * NQKV + 4096 + h * HD_ + 64 + j]);
        size_t o = ((size_t)(b * NKV_ + h) * S_ + s) * HD_ + j;
        Kb[o]      = f2bf(x1 * c - x2 * sn);
        Kb[o + 64] = f2bf(x2 * c + x1 * sn);
    }
}

// ---------------------------------------------------------------------------
// V transpose (unchanged): qkv V part -> Vt[b,hk,d,s]
// ---------------------------------------------------------------------------
__global__ __launch_bounds__(256) void v_transpose(
    const u16* __restrict__ qkv, u16* __restrict__ Vt)
{
    __shared__ __align__(16) u16 T[128][136];
    int bidx = blockIdx.x;
    int st = bidx & 15; int h = (bidx >> 4) & 7; int b = bidx >> 7;
    int s0 = st * 128;
    int tid = threadIdx.x;
    #pragma unroll
    for (int i = 0; i < 8; ++i) {
        int row = i * 16 + (tid >> 4); int cg = tid & 15;
        const u16* src = qkv + (size_t)(b * S_ + s0 + row) * NQKV + 5120 + h * HD_ + cg * 8;
        *(short8*)&T[row][cg * 8] = *(const short8*)src;
    }
    __syncthreads();
    #pragma unroll
    for (int i = 0; i < 8; ++i) {
        int d = i * 16 + (tid >> 4); int cg = tid & 15;
        __align__(16) u16 tmp[8];
        #pragma unroll
        for (int j = 0; j < 8; ++j) tmp[j] = T[cg * 8 + j][d];
        *(short8*)(Vt + ((size_t)(b * NKV_ + h) * HD_ + d) * S_ + s0 + cg * 8) =
            *(short8*)tmp;
    }
}

// ---------------------------------------------------------------------------
// Flash attention v2.  Key changes vs v1:
//  * S^T = mfma(A=K, B=Q): C-layout col=q(l16), row=kv(quad*4+r) ->
//    softmax reduce = in-register over 8 + TWO __shfl_xor (was 32 tree ops)
//  * O^T = mfma(A=Vt, B=P^T); P^T round-trips LDS as [q][kv]:
//    2x ds_write_b64 + 1x ds_read_b128 per iter (was 16 scalar writes)
//  * per-lane scalar m,l state (replicated across quads)
//  * wave handles q-tile pair (p, 127-p): exactly 65 KV-32 iters per wave,
//    perfectly uniform load -> occupancy stays flat
//  * causal mask only on the diagonal tile (t<tmax provably unmasked)
// ---------------------------------------------------------------------------
__global__ __launch_bounds__(256) void flash_attn(
    const u16* __restrict__ Q, const u16* __restrict__ Kb,
    const u16* __restrict__ Vt, u16* __restrict__ AO)
{
    __shared__ __align__(16) u16 Pq[4][16][40];   // [wave][q][kv 32 + pad 8]
    const int tid  = threadIdx.x;
    const int wave = tid >> 6, lane = tid & 63;
    const int quad = lane >> 4, l16 = lane & 15;
    int gw = blockIdx.x * 4 + wave;               // [0, 4096)
    int p  = gw & 63;
    int h  = (gw >> 6) & (NH_ - 1);
    int b  = gw >> 11;
    int hk = h >> 2;

    const u16* Kbase = Kb + (size_t)(b * NKV_ + hk) * S_ * HD_;
    const u16* Vbase = Vt + (size_t)(b * NKV_ + hk) * HD_ * S_;
    u16* Pw = &Pq[wave][0][0];

    #pragma unroll 1
    for (int half = 0; half < 2; ++half) {
        const int qt = half ? (127 - p) : p;
        const int q0 = qt * 16;

        const u16* Qp = Q + ((size_t)(b * NH_ + h) * S_ + q0 + l16) * HD_ + quad * 8;
        short8 qf[4];
        #pragma unroll
        for (int c = 0; c < 4; ++c) qf[c] = *(const short8*)(Qp + c * 32);

        float m = -1e30f, l = 0.f;
        floatx4 o[8];
        #pragma unroll
        for (int nc = 0; nc < 8; ++nc) o[nc] = (floatx4){0.f, 0.f, 0.f, 0.f};

        const int tmax = (q0 + 15) >> 5;
        for (int t = 0; t <= tmax; ++t) {
            const int kb = t * 32;
            floatx4 s0 = (floatx4){0.f, 0.f, 0.f, 0.f};
            floatx4 s1 = (floatx4){0.f, 0.f, 0.f, 0.f};
            const u16* Kp = Kbase + (size_t)(kb + l16) * HD_ + quad * 8;
            #pragma unroll
            for (int c = 0; c < 4; ++c)
                s0 = __builtin_amdgcn_mfma_f32_16x16x32_bf16(
                    *(const short8*)(Kp + c * 32), qf[c], s0, 0, 0, 0);
            #pragma unroll
            for (int c = 0; c < 4; ++c)
                s1 = __builtin_amdgcn_mfma_f32_16x16x32_bf16(
                    *(const short8*)(Kp + 16 * HD_ + c * 32), qf[c], s1, 0, 0, 0);

            if (t == tmax) {      // diagonal tile: apply causal mask
                const int qpos = q0 + l16;
                #pragma unroll
                for (int r = 0; r < 4; ++r) {
                    if (kb + quad * 4 + r > qpos)      s0[r] = -1e38f;
                    if (kb + 16 + quad * 4 + r > qpos) s1[r] = -1e38f;
                }
            }

            // row (=q) max: in-register over 8, then 2 cross-quad shuffles
            float bm = fmaxf(fmaxf(fmaxf(s0[0], s0[1]), fmaxf(s0[2], s0[3])),
                             fmaxf(fmaxf(s1[0], s1[1]), fmaxf(s1[2], s1[3])));
            bm = fmaxf(bm, __shfl_xor(bm, 16));
            bm = fmaxf(bm, __shfl_xor(bm, 32));
            const float mn = fmaxf(m, bm * SCALE);
            const float al = __expf(m - mn);
            m = mn;

            float pr0[4], pr1[4];
            float rs = 0.f;
            #pragma unroll
            for (int r = 0; r < 4; ++r) {
                pr0[r] = __expf(fmaf(s0[r], SCALE, -mn));
                pr1[r] = __expf(fmaf(s1[r], SCALE, -mn));
                rs += pr0[r] + pr1[r];
            }
            rs += __shfl_xor(rs, 16);
            rs += __shfl_xor(rs, 32);
            l = l * al + rs;
            #pragma unroll
            for (int nc = 0; nc < 8; ++nc)
                #pragma unroll
                for (int r = 0; r < 4; ++r) o[nc][r] *= al;

            // P^T -> LDS [q][kv]: lane writes 4 contiguous kv per sub-tile
            {
                u32 a0 = (u32)f2bf(pr0[0]) | ((u32)f2bf(pr0[1]) << 16);
                u32 a1 = (u32)f2bf(pr0[2]) | ((u32)f2bf(pr0[3]) << 16);
                u32 b0 = (u32)f2bf(pr1[0]) | ((u32)f2bf(pr1[1]) << 16);
                u32 b1 = (u32)f2bf(pr1[2]) | ((u32)f2bf(pr1[3]) << 16);
                *(uint2*)&Pw[l16 * 40 + quad * 4]      = make_uint2(a0, a1);
                *(uint2*)&Pw[l16 * 40 + 16 + quad * 4] = make_uint2(b0, b1);
            }
            short8 pf = *(const short8*)&Pw[l16 * 40 + quad * 8];

            #pragma unroll
            for (int nc = 0; nc < 8; ++nc) {
                short8 vf = *(const short8*)(
                    Vbase + (size_t)(nc * 16 + l16) * S_ + kb + quad * 8);
                o[nc] = __builtin_amdgcn_mfma_f32_16x16x32_bf16(vf, pf, o[nc], 0, 0, 0);
            }
        }

        // write O^T: lane holds (d = nc*16 + quad*4 + r, q = l16)
        const float inv = 1.0f / l;
        u16* dst = AO + ((size_t)(b * S_) + q0 + l16) * (NH_ * HD_) + h * HD_;
        #pragma unroll
        for (int nc = 0; nc < 8; ++nc) {
            u32 lo = (u32)f2bf(o[nc][0] * inv) | ((u32)f2bf(o[nc][1] * inv) << 16);
            u32 hi = (u32)f2bf(o[nc][2] * inv) | ((u32)f2bf(o[nc][3] * inv) << 16);
            *(uint2*)(dst + nc * 16 + quad * 4) = make_uint2(lo, hi);
        }
    }
}

// ---------------------------------------------------------------------------
extern "C" void kernel_launch(void* const* d_in, const int* in_sizes, int n_in,
                              void* d_out, int out_size, void* d_ws, size_t ws_size,
                              hipStream_t stream)
{
    const float* hs   = (const float*)d_in[0];
    const float* cosp = (const float*)d_in[1];
    const float* sinp = (const float*)d_in[2];
    const float* wq   = (const float*)d_in[3];
    const float* wk   = (const float*)d_in[4];
    const float* wv   = (const float*)d_in[5];
    const float* wo   = (const float*)d_in[6];
    float* out = (float*)d_out;
    char* ws = (char*)d_ws;

    u16* qkv_raw = (u16*)ws;                                  // 48 MB
    u16* AO      = (u16*)ws;                                  // 32 MB (reuse)
    u16* Qb = (u16*)(ws + (size_t)48 * 1024 * 1024);          // 32 MB
    u16* Kb = (u16*)(ws + (size_t)80 * 1024 * 1024);          //  8 MB
    u16* Vt = (u16*)(ws + (size_t)88 * 1024 * 1024);          //  8 MB

    gemm_bt<false, false><<<dim3(NQKV / 128, M_TOK / 128), 256, 0, stream>>>(
        hs, wq, wk, wv, NH_ * HD_, NH_ * HD_ + NKV_ * HD_,
        qkv_raw, M_TOK, NQKV, D_);

    rope_reshape<<<40960, 256, 0, stream>>>(qkv_raw, cosp, sinp, Qb, Kb);

    v_transpose<<<256, 256, 0, stream>>>(qkv_raw, Vt);

    flash_attn<<<1024, 256, 0, stream>>>(Qb, Kb, Vt, AO);

    gemm_bt<true, true><<<dim3(D_ / 128, M_TOK / 128), 256, 0, stream>>>(
        AO, wo, wo, wo, D_, 2 * D_, out, M_TOK, D_, NH_ * HD_);
}